// Round 8
// baseline (1339.034 us; speedup 1.0000x reference)
//
#include <hip/hip_runtime.h>

#define D       128
#define NNODES  50000
#define NEDGES  600000
#define TE      64
#define TN      64
#define BLK     256
#define LN_EPS  1e-5f

typedef float  fx4    __attribute__((ext_vector_type(4)));
typedef float  f32x4  __attribute__((ext_vector_type(4)));
typedef __bf16 bf16x4 __attribute__((ext_vector_type(4)));
typedef __bf16 bf16x8 __attribute__((ext_vector_type(8)));

// ---- d_ws layout ----
#define EW1F_OFF 0                         // K=384: 12 ksteps * 8 nf
#define EW2F_OFF (128 * 384)
#define NW1F_OFF (EW2F_OFF + 128 * 128)
#define NW2F_OFF (NW1F_OFF + 128 * 256)
#define WS_ELEMS (NW2F_OFF + 128 * 128)    // 114688 bf16
#define W_BYTES  (WS_ELEMS * 2)
// bf16 precompute (byte offsets)
#define PDB_OFF     ((size_t)W_BYTES)
#define PSB_OFF     (PDB_OFF + (size_t)NNODES * D * 2)
// CSR arrays
#define COUNTS_OFF  (PSB_OFF + (size_t)NNODES * D * 2)
#define OFFS_OFF    (COUNTS_OFF + 4 * (size_t)NNODES)
#define CURS_OFF    (OFFS_OFF   + 4 * ((size_t)NNODES + 1))
#define ELIST_OFF   (CURS_OFF   + 4 * (size_t)NNODES)
#define WS_NEED     (ELIST_OFF  + 4 * (size_t)NEDGES)     // ~28.8 MB

__device__ __forceinline__ float silu_f(float z) {
    return z * (1.0f / (1.0f + __expf(-z)));
}

// ---------------------------------------------------------------------------
// Weight prep: f32 [K][128] -> bf16 fragment-major frag[ks][nf][lane][8]
// ---------------------------------------------------------------------------
__global__ __launch_bounds__(256) void prep_weights(
    const float* __restrict__ eW1, const float* __restrict__ eW2,
    const float* __restrict__ nW1, const float* __restrict__ nW2,
    __bf16* __restrict__ ws)
{
    int idx = blockIdx.x * 256 + threadIdx.x;
    if (idx >= WS_ELEMS) return;
    const float* src;
    int local;
    if (idx < EW2F_OFF)      { src = eW1; local = idx; }
    else if (idx < NW1F_OFF) { src = eW2; local = idx - EW2F_OFF; }
    else if (idx < NW2F_OFF) { src = nW1; local = idx - NW1F_OFF; }
    else                     { src = nW2; local = idx - NW2F_OFF; }
    const int f   = local >> 9;
    const int rem = local & 511;
    const int l   = rem >> 3;
    const int j   = rem & 7;
    const int ks  = f >> 3;
    const int nf  = f & 7;
    const int n   = (nf << 4) + (l & 15);
    const int k   = (ks << 5) + ((l >> 4) << 3) + j;
    ws[idx] = (__bf16)src[(size_t)k * D + n];
}

// ---------------------------------------------------------------------------
// CSR build: histogram -> exclusive scan -> scatter
// ---------------------------------------------------------------------------
__global__ __launch_bounds__(256) void hist_kernel(
    const int* __restrict__ edge_index, int* __restrict__ counts)
{
    int i = blockIdx.x * 256 + threadIdx.x;
    if (i < NEDGES) atomicAdd(&counts[edge_index[NEDGES + i]], 1);
}

__global__ __launch_bounds__(256) void scan_kernel(
    const int* __restrict__ counts, int* __restrict__ offs, int* __restrict__ curs)
{
    __shared__ int sh[256];
    const int t = threadIdx.x;
    const int STRIP = (NNODES + 255) / 256;
    const int base = t * STRIP;

    int tsum = 0;
    for (int i = 0; i < STRIP; ++i) {
        int idx = base + i;
        if (idx < NNODES) tsum += counts[idx];
    }
    sh[t] = tsum;
    __syncthreads();
    for (int off = 1; off < 256; off <<= 1) {
        int add = (t >= off) ? sh[t - off] : 0;
        __syncthreads();
        sh[t] += add;
        __syncthreads();
    }
    int run = (t > 0) ? sh[t - 1] : 0;
    for (int i = 0; i < STRIP; ++i) {
        int idx = base + i;
        if (idx < NNODES) {
            offs[idx] = run;
            curs[idx] = run;
            run += counts[idx];
        }
    }
    if (t == 255) offs[NNODES] = run;
}

__global__ __launch_bounds__(256) void scatter_kernel(
    const int* __restrict__ edge_index, int* __restrict__ curs,
    int* __restrict__ elist)
{
    int i = blockIdx.x * 256 + threadIdx.x;
    if (i < NEDGES) {
        int pos = atomicAdd(&curs[edge_index[NEDGES + i]], 1);
        elist[pos] = i;
    }
}

// ---------------------------------------------------------------------------
// Per-node precompute (bf16 out): PdB[n] = x[n]@W1[0:128]+b1 ; PsB = x[n]@W1[128:256]
// ---------------------------------------------------------------------------
__global__ __launch_bounds__(256) void pre_nodes(
    const float* __restrict__ x,
    const __bf16* __restrict__ W1f,
    const float* __restrict__ b1,
    __bf16* __restrict__ PdB,
    __bf16* __restrict__ PsB)
{
    __shared__ __bf16 xt[TN][136];

    const int tid = threadIdx.x;
    const int r0g = blockIdx.x * TN;
    const int lane  = tid & 63;
    const int wid   = tid >> 6;
    const int wrow0 = wid << 4;
    const int c16   = lane & 15;
    const int kq    = lane >> 4;
    const int ks8   = kq << 3;
    const int lo8   = lane << 3;

    #pragma unroll
    for (int pass = 0; pass < 8; ++pass) {
        const int row = wrow0 + (pass << 1) + (lane >> 5);
        const int gr  = r0g + row;
        const int c4  = (lane & 31) << 2;
        fx4 v = {0.f, 0.f, 0.f, 0.f};
        if (gr < NNODES) v = *(const fx4*)&x[(size_t)gr * D + c4];
        bf16x4 h;
        #pragma unroll
        for (int j = 0; j < 4; ++j) h[j] = (__bf16)v[j];
        *(bf16x4*)&xt[row][c4] = h;
    }

    f32x4 acc_d[8], acc_s[8];
    #pragma unroll
    for (int nf = 0; nf < 8; ++nf) {
        acc_d[nf] = (f32x4){0.f, 0.f, 0.f, 0.f};
        acc_s[nf] = (f32x4){0.f, 0.f, 0.f, 0.f};
    }

    #pragma unroll
    for (int ks = 0; ks < 4; ++ks) {
        bf16x8 a = *(const bf16x8*)&xt[wrow0 + c16][(ks << 5) + ks8];
        const __bf16* wpd = W1f + ((size_t)(ks << 3) << 9) + lo8;
        const __bf16* wps = W1f + ((size_t)((4 + ks) << 3) << 9) + lo8;
        #pragma unroll
        for (int nf = 0; nf < 8; ++nf) {
            bf16x8 bd = *(const bf16x8*)(wpd + (nf << 9));
            bf16x8 bs = *(const bf16x8*)(wps + (nf << 9));
            acc_d[nf] = __builtin_amdgcn_mfma_f32_16x16x32_bf16(a, bd, acc_d[nf], 0, 0, 0);
            acc_s[nf] = __builtin_amdgcn_mfma_f32_16x16x32_bf16(a, bs, acc_s[nf], 0, 0, 0);
        }
    }

    #pragma unroll
    for (int nf = 0; nf < 8; ++nf) {
        const int col = nf * 16 + c16;
        const float bb = b1[col];
        #pragma unroll
        for (int r = 0; r < 4; ++r) {
            const int row = r0g + wrow0 + kq * 4 + r;
            if (row < NNODES) {
                PdB[(size_t)row * D + col] = (__bf16)(acc_d[nf][r] + bb);
                PsB[(size_t)row * D + col] = (__bf16)acc_s[nf][r];
            }
        }
    }
}

// ---------------------------------------------------------------------------
// CSR edge kernel: one block = 64 consecutive dst nodes. Processes that
// range's edges in chunks of 64 rows. NO global atomics: agg accumulated in
// LDS (ds atomics; block exclusively owns its dst rows) then stored plain.
// Barrier-free main loop (sum_t/ce/cd/cs rows are wave-private).
// ---------------------------------------------------------------------------
__global__ __launch_bounds__(BLK, 3) void edge_kernel_csr(
    const float* __restrict__ edge_attr,
    const int*   __restrict__ edge_index,
    const __bf16* __restrict__ PdB,
    const __bf16* __restrict__ PsB,
    const __bf16* __restrict__ W1f,   // W1e = ksteps 8..11
    const __bf16* __restrict__ W2f,
    const float* __restrict__ b2,
    const float* __restrict__ lng, const float* __restrict__ lnb,
    const int*   __restrict__ offs,
    const int*   __restrict__ elist,
    float* __restrict__ edges_out,
    float* __restrict__ agg)
{
    __shared__ float  aggF[64][132];    // padded stride: 132 % 32 = 4
    __shared__ __bf16 sum_t[64][136];   // gather sum, then h1 in place
    __shared__ int    ce[64], cd[64], cs[64];

    const int tid = threadIdx.x;
    const int n0  = blockIdx.x * 64;

    #pragma unroll
    for (int i = tid; i < 64 * 132; i += BLK) ((float*)aggF)[i] = 0.f;
    __syncthreads();

    const int lane  = tid & 63;
    const int wid   = tid >> 6;
    const int wrow0 = wid << 4;
    const int c16   = lane & 15;
    const int kq    = lane >> 4;
    const int ks8   = kq << 3;
    const int lo8   = lane << 3;

    const int nHi  = (n0 + 64 < NNODES) ? n0 + 64 : NNODES;
    const int eBeg = offs[n0];
    const int eEnd = offs[nHi];

    float b2v[8], gv[8], bvv[8];
    #pragma unroll
    for (int nf = 0; nf < 8; ++nf) {
        b2v[nf] = b2[nf * 16 + c16];
        gv[nf]  = lng[nf * 16 + c16];
        bvv[nf] = lnb[nf * 16 + c16];
    }

    for (int c = eBeg; c < eEnd; c += 64) {
        // ---- load ids for this wave's 16 rows ----
        if (lane < 16) {
            const int row = wrow0 + lane;
            int p = c + row;
            if (p >= eEnd) p = eEnd - 1;          // clamp (stores guarded later)
            const int eid = elist[p];
            ce[row] = eid;
            cd[row] = edge_index[NEDGES + eid];   // dst
            cs[row] = edge_index[eid];            // src
        }

        // ---- gather PdB[dst]+PsB[src] -> sum_t (wave-private rows) ----
        #pragma unroll
        for (int pass = 0; pass < 8; ++pass) {
            const int row = wrow0 + (pass << 1) + (lane >> 5);
            const int dn = cd[row], sn = cs[row];
            const int c4 = (lane & 31) << 2;
            bf16x4 a = *(const bf16x4*)&PdB[(size_t)dn * D + c4];
            bf16x4 b = *(const bf16x4*)&PsB[(size_t)sn * D + c4];
            bf16x4 h;
            #pragma unroll
            for (int j = 0; j < 4; ++j) h[j] = (__bf16)((float)a[j] + (float)b[j]);
            *(bf16x4*)&sum_t[row][c4] = h;
        }

        // ---- edge_attr A-fragments (row via eid indirection) ----
        bf16x8 aE[4];
        {
            const float* ep = edge_attr + (size_t)ce[wrow0 + c16] * D + ks8;
            #pragma unroll
            for (int ks2 = 0; ks2 < 4; ++ks2) {
                fx4 v0 = *(const fx4*)(ep + (ks2 << 5));
                fx4 v1 = *(const fx4*)(ep + (ks2 << 5) + 4);
                bf16x8 a;
                #pragma unroll
                for (int j = 0; j < 4; ++j) { a[j] = (__bf16)v0[j]; a[j + 4] = (__bf16)v1[j]; }
                aE[ks2] = a;
            }
        }

        // ---- GEMM1e: edge_attr @ W1e ----
        f32x4 acc[8];
        #pragma unroll
        for (int nf = 0; nf < 8; ++nf) acc[nf] = (f32x4){0.f, 0.f, 0.f, 0.f};

        #pragma unroll
        for (int ks2 = 0; ks2 < 4; ++ks2) {
            const __bf16* wp = W1f + ((size_t)((8 + ks2) << 3) << 9) + lo8;
            #pragma unroll
            for (int nf = 0; nf < 8; ++nf) {
                bf16x8 b = *(const bf16x8*)(wp + (nf << 9));
                acc[nf] = __builtin_amdgcn_mfma_f32_16x16x32_bf16(aE[ks2], b, acc[nf], 0, 0, 0);
            }
        }

        // ---- h1 = silu(acc + sum) in place ----
        #pragma unroll
        for (int nf = 0; nf < 8; ++nf) {
            #pragma unroll
            for (int r = 0; r < 4; ++r) {
                const int row = wrow0 + kq * 4 + r;
                const int col = nf * 16 + c16;
                float z = acc[nf][r] + (float)sum_t[row][col];
                sum_t[row][col] = (__bf16)silu_f(z);
            }
        }

        // ---- GEMM2: h1 @ W2 ----
        f32x4 acc2[8];
        #pragma unroll
        for (int nf = 0; nf < 8; ++nf) acc2[nf] = (f32x4){0.f, 0.f, 0.f, 0.f};

        #pragma unroll
        for (int ks = 0; ks < 4; ++ks) {
            bf16x8 a = *(const bf16x8*)&sum_t[wrow0 + c16][(ks << 5) + ks8];
            const __bf16* wp = W2f + ((size_t)(ks << 3) << 9) + lo8;
            #pragma unroll
            for (int nf = 0; nf < 8; ++nf) {
                bf16x8 b = *(const bf16x8*)(wp + (nf << 9));
                acc2[nf] = __builtin_amdgcn_mfma_f32_16x16x32_bf16(a, b, acc2[nf], 0, 0, 0);
            }
        }

        // ---- bias + LN + scatter-store + LDS agg ----
        float s[4] = {0.f, 0.f, 0.f, 0.f}, q[4] = {0.f, 0.f, 0.f, 0.f};
        #pragma unroll
        for (int nf = 0; nf < 8; ++nf)
            #pragma unroll
            for (int r = 0; r < 4; ++r) {
                float zz = acc2[nf][r] + b2v[nf];
                acc2[nf][r] = zz;
                s[r] += zz;
                q[r] += zz * zz;
            }
        #pragma unroll
        for (int m = 1; m <= 8; m <<= 1)
            #pragma unroll
            for (int r = 0; r < 4; ++r) {
                s[r] += __shfl_xor(s[r], m, 64);
                q[r] += __shfl_xor(q[r], m, 64);
            }

        #pragma unroll
        for (int r = 0; r < 4; ++r) {
            const int row = wrow0 + kq * 4 + r;
            if (c + row < eEnd) {
                const float mu   = s[r] * (1.0f / 128.0f);
                const float var  = q[r] * (1.0f / 128.0f) - mu * mu;
                const float rstd = rsqrtf(var + LN_EPS);
                const int eid = ce[row];
                const int dl  = cd[row] - n0;
                const size_t erow = (size_t)eid * D;
                #pragma unroll
                for (int nf = 0; nf < 8; ++nf) {
                    const int col = nf * 16 + c16;
                    float o = (acc2[nf][r] - mu) * rstd * gv[nf] + bvv[nf];
                    edges_out[erow + col] = o;
                    atomicAdd(&aggF[dl][col], o);   // LDS atomic
                }
            }
        }
    }

    __syncthreads();
    // ---- plain coalesced agg store (block exclusively owns these rows) ----
    #pragma unroll
    for (int i = tid; i < 64 * 128; i += BLK) {
        const int row = i >> 7, col = i & 127;
        const int g = n0 + row;
        if (g < NNODES) agg[(size_t)g * D + col] = aggF[row][col];
    }
}

// ---------------------------------------------------------------------------
// Fallback edge kernel (round-6 structure, atomics) when ws too small
// ---------------------------------------------------------------------------
__global__ __launch_bounds__(BLK, 4) void edge_kernel_fb(
    const float* __restrict__ x,
    const float* __restrict__ edge_attr,
    const int*   __restrict__ edge_index,
    const __bf16* __restrict__ W1f,
    const float* __restrict__ b1,
    const __bf16* __restrict__ W2f,
    const float* __restrict__ b2,
    const float* __restrict__ lng, const float* __restrict__ lnb,
    float* __restrict__ edges_out,
    float* __restrict__ agg)
{
    __shared__ __bf16 in_t[TE][264];
    __shared__ int    src_s[TE], dst_s[TE];

    const int tid = threadIdx.x;
    const int e0g = blockIdx.x * TE;

    if (tid < TE) {
        src_s[tid] = edge_index[e0g + tid];
        dst_s[tid] = edge_index[NEDGES + e0g + tid];
    }
    __syncthreads();

    const int lane  = tid & 63;
    const int wid   = tid >> 6;
    const int wrow0 = wid << 4;
    const int c16   = lane & 15;
    const int kq    = lane >> 4;
    const int ks8   = kq << 3;
    const int lo8   = lane << 3;

    bf16x8 aE[4];
    {
        const float* ep = edge_attr + (size_t)(e0g + wrow0 + c16) * D + ks8;
        #pragma unroll
        for (int ks2 = 0; ks2 < 4; ++ks2) {
            fx4 v0 = *(const fx4*)(ep + (ks2 << 5));
            fx4 v1 = *(const fx4*)(ep + (ks2 << 5) + 4);
            bf16x8 a;
            #pragma unroll
            for (int j = 0; j < 4; ++j) { a[j] = (__bf16)v0[j]; a[j + 4] = (__bf16)v1[j]; }
            aE[ks2] = a;
        }
    }

    #pragma unroll
    for (int it = 0; it < 8; ++it) {
        const int idx = tid + it * BLK;
        const int e   = idx >> 5;
        const int c4  = (idx & 31) << 2;
        fx4 v = *(const fx4*)&x[(size_t)dst_s[e] * D + c4];
        bf16x4 h;
        #pragma unroll
        for (int j = 0; j < 4; ++j) h[j] = (__bf16)v[j];
        *(bf16x4*)&in_t[e][c4] = h;
    }
    #pragma unroll
    for (int it = 0; it < 8; ++it) {
        const int idx = tid + it * BLK;
        const int e   = idx >> 5;
        const int c4  = (idx & 31) << 2;
        fx4 v = *(const fx4*)&x[(size_t)src_s[e] * D + c4];
        bf16x4 h;
        #pragma unroll
        for (int j = 0; j < 4; ++j) h[j] = (__bf16)v[j];
        *(bf16x4*)&in_t[e][128 + c4] = h;
    }
    __syncthreads();

    f32x4 acc[8];
    #pragma unroll
    for (int nf = 0; nf < 8; ++nf) acc[nf] = (f32x4){0.f, 0.f, 0.f, 0.f};

    #pragma unroll
    for (int ks = 0; ks < 12; ++ks) {
        bf16x8 a = (ks < 8) ? *(const bf16x8*)&in_t[wrow0 + c16][(ks << 5) + ks8]
                            : aE[ks - 8];
        const __bf16* wp = W1f + ((size_t)(ks << 3) << 9) + lo8;
        #pragma unroll
        for (int nf = 0; nf < 8; ++nf) {
            bf16x8 b = *(const bf16x8*)(wp + (nf << 9));
            acc[nf] = __builtin_amdgcn_mfma_f32_16x16x32_bf16(a, b, acc[nf], 0, 0, 0);
        }
    }

    #pragma unroll
    for (int nf = 0; nf < 8; ++nf) {
        const float bb = b1[nf * 16 + c16];
        #pragma unroll
        for (int r = 0; r < 4; ++r) {
            float h = silu_f(acc[nf][r] + bb);
            in_t[wrow0 + kq * 4 + r][nf * 16 + c16] = (__bf16)h;
        }
    }

    f32x4 acc2[8];
    #pragma unroll
    for (int nf = 0; nf < 8; ++nf) acc2[nf] = (f32x4){0.f, 0.f, 0.f, 0.f};

    #pragma unroll
    for (int ks = 0; ks < 4; ++ks) {
        bf16x8 a = *(const bf16x8*)&in_t[wrow0 + c16][(ks << 5) + ks8];
        const __bf16* wp = W2f + ((size_t)(ks << 3) << 9) + lo8;
        #pragma unroll
        for (int nf = 0; nf < 8; ++nf) {
            bf16x8 b = *(const bf16x8*)(wp + (nf << 9));
            acc2[nf] = __builtin_amdgcn_mfma_f32_16x16x32_bf16(a, b, acc2[nf], 0, 0, 0);
        }
    }

    float b2v[8], gv[8], bvv[8];
    #pragma unroll
    for (int nf = 0; nf < 8; ++nf) {
        b2v[nf] = b2[nf * 16 + c16];
        gv[nf]  = lng[nf * 16 + c16];
        bvv[nf] = lnb[nf * 16 + c16];
    }

    float s[4] = {0.f, 0.f, 0.f, 0.f}, q[4] = {0.f, 0.f, 0.f, 0.f};
    #pragma unroll
    for (int nf = 0; nf < 8; ++nf)
        #pragma unroll
        for (int r = 0; r < 4; ++r) {
            float zz = acc2[nf][r] + b2v[nf];
            acc2[nf][r] = zz;
            s[r] += zz;
            q[r] += zz * zz;
        }
    #pragma unroll
    for (int m = 1; m <= 8; m <<= 1)
        #pragma unroll
        for (int r = 0; r < 4; ++r) {
            s[r] += __shfl_xor(s[r], m, 64);
            q[r] += __shfl_xor(q[r], m, 64);
        }

    #pragma unroll
    for (int r = 0; r < 4; ++r) {
        const float mu   = s[r] * (1.0f / 128.0f);
        const float var  = q[r] * (1.0f / 128.0f) - mu * mu;
        const float rstd = rsqrtf(var + LN_EPS);
        const int row = wrow0 + kq * 4 + r;
        const size_t erow = (size_t)(e0g + row) * D;
        float* ap = agg + (size_t)dst_s[row] * D;
        #pragma unroll
        for (int nf = 0; nf < 8; ++nf) {
            const int col = nf * 16 + c16;
            float o = (acc2[nf][r] - mu) * rstd * gv[nf] + bvv[nf];
            edges_out[erow + col] = o;
            atomicAdd(ap + col, o);
        }
    }
}

// ---------------------------------------------------------------------------
// Node kernel: 64 nodes/block; in = [x, agg] (256)
// ---------------------------------------------------------------------------
__global__ __launch_bounds__(BLK, 4) void node_kernel(
    const float* __restrict__ x,
    const float* __restrict__ agg,
    const __bf16* __restrict__ W1f,
    const float* __restrict__ b1,
    const __bf16* __restrict__ W2f,
    const float* __restrict__ b2,
    const float* __restrict__ lng, const float* __restrict__ lnb,
    float* __restrict__ nodes_out)
{
    __shared__ __bf16 in_t[TN][264];

    const int tid = threadIdx.x;
    const int r0g = blockIdx.x * TN;

    #pragma unroll
    for (int it = 0; it < 8; ++it) {
        const int idx = tid + it * BLK;
        const int e   = idx >> 5;
        const int c4  = (idx & 31) << 2;
        const int row = r0g + e;
        fx4 v = {0.f, 0.f, 0.f, 0.f};
        if (row < NNODES) v = *(const fx4*)&x[(size_t)row * D + c4];
        bf16x4 h;
        #pragma unroll
        for (int j = 0; j < 4; ++j) h[j] = (__bf16)v[j];
        *(bf16x4*)&in_t[e][c4] = h;
    }
    #pragma unroll
    for (int it = 0; it < 8; ++it) {
        const int idx = tid + it * BLK;
        const int e   = idx >> 5;
        const int c4  = (idx & 31) << 2;
        const int row = r0g + e;
        fx4 v = {0.f, 0.f, 0.f, 0.f};
        if (row < NNODES) v = *(const fx4*)&agg[(size_t)row * D + c4];
        bf16x4 h;
        #pragma unroll
        for (int j = 0; j < 4; ++j) h[j] = (__bf16)v[j];
        *(bf16x4*)&in_t[e][128 + c4] = h;
    }
    __syncthreads();

    const int lane  = tid & 63;
    const int wid   = tid >> 6;
    const int wrow0 = wid << 4;
    const int c16   = lane & 15;
    const int kq    = lane >> 4;
    const int ks8   = kq << 3;
    const int lo8   = lane << 3;

    f32x4 acc[8];
    #pragma unroll
    for (int nf = 0; nf < 8; ++nf) acc[nf] = (f32x4){0.f, 0.f, 0.f, 0.f};

    #pragma unroll
    for (int ks = 0; ks < 8; ++ks) {
        bf16x8 a = *(const bf16x8*)&in_t[wrow0 + c16][(ks << 5) + ks8];
        const __bf16* wp = W1f + ((size_t)(ks << 3) << 9) + lo8;
        #pragma unroll
        for (int nf = 0; nf < 8; ++nf) {
            bf16x8 b = *(const bf16x8*)(wp + (nf << 9));
            acc[nf] = __builtin_amdgcn_mfma_f32_16x16x32_bf16(a, b, acc[nf], 0, 0, 0);
        }
    }

    #pragma unroll
    for (int nf = 0; nf < 8; ++nf) {
        const float bb = b1[nf * 16 + c16];
        #pragma unroll
        for (int r = 0; r < 4; ++r) {
            float h = silu_f(acc[nf][r] + bb);
            in_t[wrow0 + kq * 4 + r][nf * 16 + c16] = (__bf16)h;
        }
    }

    f32x4 acc2[8];
    #pragma unroll
    for (int nf = 0; nf < 8; ++nf) acc2[nf] = (f32x4){0.f, 0.f, 0.f, 0.f};

    #pragma unroll
    for (int ks = 0; ks < 4; ++ks) {
        bf16x8 a = *(const bf16x8*)&in_t[wrow0 + c16][(ks << 5) + ks8];
        const __bf16* wp = W2f + ((size_t)(ks << 3) << 9) + lo8;
        #pragma unroll
        for (int nf = 0; nf < 8; ++nf) {
            bf16x8 b = *(const bf16x8*)(wp + (nf << 9));
            acc2[nf] = __builtin_amdgcn_mfma_f32_16x16x32_bf16(a, b, acc2[nf], 0, 0, 0);
        }
    }

    float b2v[8], gv[8], bvv[8];
    #pragma unroll
    for (int nf = 0; nf < 8; ++nf) {
        b2v[nf] = b2[nf * 16 + c16];
        gv[nf]  = lng[nf * 16 + c16];
        bvv[nf] = lnb[nf * 16 + c16];
    }

    float s[4] = {0.f, 0.f, 0.f, 0.f}, q[4] = {0.f, 0.f, 0.f, 0.f};
    #pragma unroll
    for (int nf = 0; nf < 8; ++nf)
        #pragma unroll
        for (int r = 0; r < 4; ++r) {
            float zz = acc2[nf][r] + b2v[nf];
            acc2[nf][r] = zz;
            s[r] += zz;
            q[r] += zz * zz;
        }
    #pragma unroll
    for (int m = 1; m <= 8; m <<= 1)
        #pragma unroll
        for (int r = 0; r < 4; ++r) {
            s[r] += __shfl_xor(s[r], m, 64);
            q[r] += __shfl_xor(q[r], m, 64);
        }

    #pragma unroll
    for (int r = 0; r < 4; ++r) {
        const float mu   = s[r] * (1.0f / 128.0f);
        const float var  = q[r] * (1.0f / 128.0f) - mu * mu;
        const float rstd = rsqrtf(var + LN_EPS);
        const int row = r0g + wrow0 + kq * 4 + r;
        if (row >= NNODES) continue;
        const size_t orow = (size_t)row * D;
        #pragma unroll
        for (int nf = 0; nf < 8; ++nf) {
            const int col = nf * 16 + c16;
            float o = (acc2[nf][r] - mu) * rstd * gv[nf] + bvv[nf] + x[orow + col];
            nodes_out[orow + col] = o;
        }
    }
}

extern "C" void kernel_launch(void* const* d_in, const int* in_sizes, int n_in,
                              void* d_out, int out_size, void* d_ws, size_t ws_size,
                              hipStream_t stream) {
    (void)in_sizes; (void)n_in; (void)out_size;

    const float* x         = (const float*)d_in[0];
    const float* edge_attr = (const float*)d_in[1];
    const int*   edge_idx  = (const int*)  d_in[2];
    const float* eW1 = (const float*)d_in[3];
    const float* eb1 = (const float*)d_in[4];
    const float* eW2 = (const float*)d_in[5];
    const float* eb2 = (const float*)d_in[6];
    const float* elg = (const float*)d_in[7];
    const float* elb = (const float*)d_in[8];
    const float* nW1 = (const float*)d_in[9];
    const float* nb1 = (const float*)d_in[10];
    const float* nW2 = (const float*)d_in[11];
    const float* nb2 = (const float*)d_in[12];
    const float* nlg = (const float*)d_in[13];
    const float* nlb = (const float*)d_in[14];

    float* out       = (float*)d_out;
    float* nodes_out = out;                        // doubles as agg buffer
    float* edges_out = out + (size_t)NNODES * D;

    char*   wsb = (char*)d_ws;
    __bf16* ws  = (__bf16*)d_ws;

    prep_weights<<<(WS_ELEMS + 255) / 256, 256, 0, stream>>>(eW1, eW2, nW1, nW2, ws);

    if (ws_size >= WS_NEED) {
        __bf16* PdB  = (__bf16*)(wsb + PDB_OFF);
        __bf16* PsB  = (__bf16*)(wsb + PSB_OFF);
        int* counts  = (int*)(wsb + COUNTS_OFF);
        int* offs    = (int*)(wsb + OFFS_OFF);
        int* curs    = (int*)(wsb + CURS_OFF);
        int* elist   = (int*)(wsb + ELIST_OFF);

        pre_nodes<<<(NNODES + TN - 1) / TN, BLK, 0, stream>>>(
            x, ws + EW1F_OFF, eb1, PdB, PsB);

        hipMemsetAsync(counts, 0, NNODES * sizeof(int), stream);
        hist_kernel<<<(NEDGES + 255) / 256, 256, 0, stream>>>(edge_idx, counts);
        scan_kernel<<<1, 256, 0, stream>>>(counts, offs, curs);
        scatter_kernel<<<(NEDGES + 255) / 256, 256, 0, stream>>>(edge_idx, curs, elist);

        edge_kernel_csr<<<(NNODES + 63) / 64, BLK, 0, stream>>>(
            edge_attr, edge_idx, PdB, PsB,
            ws + EW1F_OFF, ws + EW2F_OFF, eb2, elg, elb,
            offs, elist, edges_out, nodes_out);
    } else {
        hipMemsetAsync(nodes_out, 0, (size_t)NNODES * D * sizeof(float), stream);
        edge_kernel_fb<<<NEDGES / TE, BLK, 0, stream>>>(
            x, edge_attr, edge_idx,
            ws + EW1F_OFF, eb1, ws + EW2F_OFF, eb2, elg, elb,
            edges_out, nodes_out);
    }

    node_kernel<<<(NNODES + TN - 1) / TN, BLK, 0, stream>>>(
        x, nodes_out,
        ws + NW1F_OFF, nb1, ws + NW2F_OFF, nb2, nlg, nlb,
        nodes_out);
}

// Round 9
// 548.419 us; speedup vs baseline: 2.4416x; 2.4416x over previous
//
#include <hip/hip_runtime.h>

#define D       128
#define NNODES  50000
#define NEDGES  600000
#define NTILES  (NEDGES / 64)    // 9375
#define TN      64
#define BLK     256
#define LN_EPS  1e-5f

typedef float  fx4    __attribute__((ext_vector_type(4)));
typedef float  f32x4  __attribute__((ext_vector_type(4)));
typedef __bf16 bf16x4 __attribute__((ext_vector_type(4)));
typedef __bf16 bf16x8 __attribute__((ext_vector_type(8)));

// ---- d_ws layout (bf16 elements): fragment-major weights ----
#define EW1F_OFF 0                         // K=384: 12 ksteps * 8 nf
#define EW2F_OFF (128 * 384)
#define NW1F_OFF (EW2F_OFF + 128 * 128)
#define NW2F_OFF (NW1F_OFF + 128 * 256)
#define WS_ELEMS (NW2F_OFF + 128 * 128)    // 114688 bf16

__device__ __forceinline__ float silu_f(float z) {
    return z * (1.0f / (1.0f + __expf(-z)));
}

// ---------------------------------------------------------------------------
// Weight prep: f32 [K][128] -> bf16 fragment-major frag[ks][nf][lane][8]
// ---------------------------------------------------------------------------
__global__ __launch_bounds__(256) void prep_weights(
    const float* __restrict__ eW1, const float* __restrict__ eW2,
    const float* __restrict__ nW1, const float* __restrict__ nW2,
    __bf16* __restrict__ ws)
{
    int idx = blockIdx.x * 256 + threadIdx.x;
    if (idx >= WS_ELEMS) return;
    const float* src;
    int local;
    if (idx < EW2F_OFF)      { src = eW1; local = idx; }
    else if (idx < NW1F_OFF) { src = eW2; local = idx - EW2F_OFF; }
    else if (idx < NW2F_OFF) { src = nW1; local = idx - NW1F_OFF; }
    else                     { src = nW2; local = idx - NW2F_OFF; }
    const int f   = local >> 9;
    const int rem = local & 511;
    const int l   = rem >> 3;
    const int j   = rem & 7;
    const int ks  = f >> 3;
    const int nf  = f & 7;
    const int n   = (nf << 4) + (l & 15);
    const int k   = (ks << 5) + ((l >> 4) << 3) + j;
    ws[idx] = (__bf16)src[(size_t)k * D + n];
}

// ---------------------------------------------------------------------------
// Persistent edge kernel, N-split, register-resident weights.
// Grid-strides over 64-edge tiles. Wave w owns output cols [w*32,(w+1)*32):
// it holds W1 frags (12 ks x 2 nf) and W2 frags (4 ks x 2 nf) in VGPRs.
// Per tile: stage [x[dst]|x[src]|edge_attr] -> LDS; GEMM1 (M=64, K=384);
// h1 -> LDS; GEMM2 (K=128); LN via cross-wave LDS partials; store + atomics.
// 3 barriers per tile.
// ---------------------------------------------------------------------------
__global__ __launch_bounds__(BLK, 2) void edge_kernel_pw(
    const float* __restrict__ x,
    const float* __restrict__ edge_attr,
    const int*   __restrict__ edge_index,
    const __bf16* __restrict__ W1f,
    const float* __restrict__ b1,
    const __bf16* __restrict__ W2f,
    const float* __restrict__ b2,
    const float* __restrict__ lng, const float* __restrict__ lnb,
    float* __restrict__ edges_out,
    float* __restrict__ agg)
{
    __shared__ __bf16 in_t[64][392];   // 384 used (x_dst | x_src | edge_attr)
    __shared__ __bf16 h1_t[64][136];   // 128 used
    __shared__ float  pr[64][12];      // LN partials: [row][{s,q} x 4 waves], padded

    const int tid  = threadIdx.x;
    const int lane = tid & 63;
    const int w    = tid >> 6;         // wave id 0..3 -> cols [w*32,(w+1)*32)
    const int c16  = lane & 15;
    const int kq   = lane >> 4;
    const int ks8  = kq << 3;
    const int lo8  = lane << 3;

    // ---- preload this wave's weight fragments into registers (once) ----
    bf16x8 W1r[12][2], W2r[4][2];
    #pragma unroll
    for (int ks = 0; ks < 12; ++ks)
        #pragma unroll
        for (int j = 0; j < 2; ++j)
            W1r[ks][j] = *(const bf16x8*)&W1f[((size_t)(ks * 8 + 2 * w + j) << 9) + lo8];
    #pragma unroll
    for (int ks = 0; ks < 4; ++ks)
        #pragma unroll
        for (int j = 0; j < 2; ++j)
            W2r[ks][j] = *(const bf16x8*)&W2f[((size_t)(ks * 8 + 2 * w + j) << 9) + lo8];

    float b1v[2], b2v[2], gv[2], bvv[2];
    #pragma unroll
    for (int j = 0; j < 2; ++j) {
        const int col = (2 * w + j) * 16 + c16;
        b1v[j] = b1[col];
        b2v[j] = b2[col];
        gv[j]  = lng[col];
        bvv[j] = lnb[col];
    }

    for (int t = blockIdx.x; t < NTILES; t += gridDim.x) {
        const int e0g = t << 6;

        // ---- stage: 3 segments x (64 rows x 32 fx4) ----
        #pragma unroll
        for (int it = 0; it < 8; ++it) {
            const int idx = tid + (it << 8);
            const int e   = idx >> 5;
            const int c4  = (idx & 31) << 2;
            const int dn  = edge_index[NEDGES + e0g + e];
            fx4 v = *(const fx4*)&x[(size_t)dn * D + c4];
            bf16x4 h;
            #pragma unroll
            for (int j = 0; j < 4; ++j) h[j] = (__bf16)v[j];
            *(bf16x4*)&in_t[e][c4] = h;
        }
        #pragma unroll
        for (int it = 0; it < 8; ++it) {
            const int idx = tid + (it << 8);
            const int e   = idx >> 5;
            const int c4  = (idx & 31) << 2;
            const int sn  = edge_index[e0g + e];
            fx4 v = *(const fx4*)&x[(size_t)sn * D + c4];
            bf16x4 h;
            #pragma unroll
            for (int j = 0; j < 4; ++j) h[j] = (__bf16)v[j];
            *(bf16x4*)&in_t[e][128 + c4] = h;
        }
        #pragma unroll
        for (int it = 0; it < 8; ++it) {
            const int idx = tid + (it << 8);
            const int e   = idx >> 5;
            const int c4  = (idx & 31) << 2;
            fx4 v = *(const fx4*)&edge_attr[(size_t)(e0g + e) * D + c4];
            bf16x4 h;
            #pragma unroll
            for (int j = 0; j < 4; ++j) h[j] = (__bf16)v[j];
            *(bf16x4*)&in_t[e][256 + c4] = h;
        }
        __syncthreads();   // [B] stage complete

        // ---- GEMM1: [64,384] @ [384, 32 cols] per wave ----
        f32x4 acc[4][2];
        #pragma unroll
        for (int mi = 0; mi < 4; ++mi)
            #pragma unroll
            for (int j = 0; j < 2; ++j) acc[mi][j] = (f32x4){0.f, 0.f, 0.f, 0.f};

        #pragma unroll
        for (int ks = 0; ks < 12; ++ks) {
            bf16x8 a[4];
            #pragma unroll
            for (int mi = 0; mi < 4; ++mi)
                a[mi] = *(const bf16x8*)&in_t[mi * 16 + c16][(ks << 5) + ks8];
            #pragma unroll
            for (int mi = 0; mi < 4; ++mi)
                #pragma unroll
                for (int j = 0; j < 2; ++j)
                    acc[mi][j] = __builtin_amdgcn_mfma_f32_16x16x32_bf16(
                        a[mi], W1r[ks][j], acc[mi][j], 0, 0, 0);
        }

        // ---- h1 = silu(acc + b1) -> h1_t (all 64 rows, this wave's 32 cols) ----
        #pragma unroll
        for (int mi = 0; mi < 4; ++mi)
            #pragma unroll
            for (int j = 0; j < 2; ++j) {
                const int col = (2 * w + j) * 16 + c16;
                #pragma unroll
                for (int r = 0; r < 4; ++r)
                    h1_t[mi * 16 + kq * 4 + r][col] =
                        (__bf16)silu_f(acc[mi][j][r] + b1v[j]);
            }
        __syncthreads();   // [D] h1 complete (also: all in_t reads done)

        // ---- GEMM2: [64,128] @ [128, 32 cols] per wave (reuse acc) ----
        #pragma unroll
        for (int mi = 0; mi < 4; ++mi)
            #pragma unroll
            for (int j = 0; j < 2; ++j) acc[mi][j] = (f32x4){0.f, 0.f, 0.f, 0.f};

        #pragma unroll
        for (int ks = 0; ks < 4; ++ks) {
            bf16x8 a[4];
            #pragma unroll
            for (int mi = 0; mi < 4; ++mi)
                a[mi] = *(const bf16x8*)&h1_t[mi * 16 + c16][(ks << 5) + ks8];
            #pragma unroll
            for (int mi = 0; mi < 4; ++mi)
                #pragma unroll
                for (int j = 0; j < 2; ++j)
                    acc[mi][j] = __builtin_amdgcn_mfma_f32_16x16x32_bf16(
                        a[mi], W2r[ks][j], acc[mi][j], 0, 0, 0);
        }

        // ---- bias + LN partials (per-wave 32-col sums -> pr) ----
        #pragma unroll
        for (int mi = 0; mi < 4; ++mi) {
            float sl[4], ql[4];
            #pragma unroll
            for (int r = 0; r < 4; ++r) {
                float z0 = acc[mi][0][r] + b2v[0];
                float z1 = acc[mi][1][r] + b2v[1];
                acc[mi][0][r] = z0;
                acc[mi][1][r] = z1;
                sl[r] = z0 + z1;
                ql[r] = z0 * z0 + z1 * z1;
            }
            #pragma unroll
            for (int m = 1; m <= 8; m <<= 1)
                #pragma unroll
                for (int r = 0; r < 4; ++r) {
                    sl[r] += __shfl_xor(sl[r], m, 64);
                    ql[r] += __shfl_xor(ql[r], m, 64);
                }
            if (c16 == 0) {
                #pragma unroll
                for (int r = 0; r < 4; ++r) {
                    const int row = mi * 16 + kq * 4 + r;
                    pr[row][2 * w]     = sl[r];
                    pr[row][2 * w + 1] = ql[r];
                }
            }
        }
        __syncthreads();   // [E] partials complete

        // ---- LN combine + store + scatter-add ----
        #pragma unroll
        for (int mi = 0; mi < 4; ++mi) {
            #pragma unroll
            for (int r = 0; r < 4; ++r) {
                const int row = mi * 16 + kq * 4 + r;
                f32x4 p0 = *(const f32x4*)&pr[row][0];
                f32x4 p1 = *(const f32x4*)&pr[row][4];
                const float s = p0[0] + p0[2] + p1[0] + p1[2];
                const float q = p0[1] + p0[3] + p1[1] + p1[3];
                const float mu   = s * (1.0f / 128.0f);
                const float var  = q * (1.0f / 128.0f) - mu * mu;
                const float rstd = rsqrtf(var + LN_EPS);
                const int dn = edge_index[NEDGES + e0g + row];
                const size_t erow = (size_t)(e0g + row) * D;
                float* ap = agg + (size_t)dn * D;
                #pragma unroll
                for (int j = 0; j < 2; ++j) {
                    const int col = (2 * w + j) * 16 + c16;
                    float o = (acc[mi][j][r] - mu) * rstd * gv[j] + bvv[j];
                    edges_out[erow + col] = o;
                    atomicAdd(ap + col, o);
                }
            }
        }
        // loop-top safety: stage(t+1) is ordered after [D]/[E] of this tile
    }
}

// ---------------------------------------------------------------------------
// Node kernel: 64 nodes/block; in = [x, agg] (256)  (round-6 structure)
// ---------------------------------------------------------------------------
__global__ __launch_bounds__(BLK, 4) void node_kernel(
    const float* __restrict__ x,
    const float* __restrict__ agg,
    const __bf16* __restrict__ W1f,
    const float* __restrict__ b1,
    const __bf16* __restrict__ W2f,
    const float* __restrict__ b2,
    const float* __restrict__ lng, const float* __restrict__ lnb,
    float* __restrict__ nodes_out)
{
    __shared__ __bf16 in_t[TN][264];   // 256 used; h1 aliases cols 0..127

    const int tid = threadIdx.x;
    const int r0g = blockIdx.x * TN;

    #pragma unroll
    for (int it = 0; it < 8; ++it) {
        const int idx = tid + it * BLK;
        const int e   = idx >> 5;
        const int c4  = (idx & 31) << 2;
        const int row = r0g + e;
        fx4 v = {0.f, 0.f, 0.f, 0.f};
        if (row < NNODES) v = *(const fx4*)&x[(size_t)row * D + c4];
        bf16x4 h;
        #pragma unroll
        for (int j = 0; j < 4; ++j) h[j] = (__bf16)v[j];
        *(bf16x4*)&in_t[e][c4] = h;
    }
    #pragma unroll
    for (int it = 0; it < 8; ++it) {
        const int idx = tid + it * BLK;
        const int e   = idx >> 5;
        const int c4  = (idx & 31) << 2;
        const int row = r0g + e;
        fx4 v = {0.f, 0.f, 0.f, 0.f};
        if (row < NNODES) v = *(const fx4*)&agg[(size_t)row * D + c4];
        bf16x4 h;
        #pragma unroll
        for (int j = 0; j < 4; ++j) h[j] = (__bf16)v[j];
        *(bf16x4*)&in_t[e][128 + c4] = h;
    }
    __syncthreads();

    const int lane  = tid & 63;
    const int wid   = tid >> 6;
    const int wrow0 = wid << 4;
    const int c16   = lane & 15;
    const int kq    = lane >> 4;
    const int ks8   = kq << 3;
    const int lo8   = lane << 3;

    f32x4 acc[8];
    #pragma unroll
    for (int nf = 0; nf < 8; ++nf) acc[nf] = (f32x4){0.f, 0.f, 0.f, 0.f};

    #pragma unroll
    for (int ks = 0; ks < 8; ++ks) {
        bf16x8 a = *(const bf16x8*)&in_t[wrow0 + c16][(ks << 5) + ks8];
        const __bf16* wp = W1f + ((size_t)(ks << 3) << 9) + lo8;
        #pragma unroll
        for (int nf = 0; nf < 8; ++nf) {
            bf16x8 b = *(const bf16x8*)(wp + (nf << 9));
            acc[nf] = __builtin_amdgcn_mfma_f32_16x16x32_bf16(a, b, acc[nf], 0, 0, 0);
        }
    }

    #pragma unroll
    for (int nf = 0; nf < 8; ++nf) {
        const float bb = b1[nf * 16 + c16];
        #pragma unroll
        for (int r = 0; r < 4; ++r) {
            float h = silu_f(acc[nf][r] + bb);
            in_t[wrow0 + kq * 4 + r][nf * 16 + c16] = (__bf16)h;
        }
    }

    f32x4 acc2[8];
    #pragma unroll
    for (int nf = 0; nf < 8; ++nf) acc2[nf] = (f32x4){0.f, 0.f, 0.f, 0.f};

    #pragma unroll
    for (int ks = 0; ks < 4; ++ks) {
        bf16x8 a = *(const bf16x8*)&in_t[wrow0 + c16][(ks << 5) + ks8];
        const __bf16* wp = W2f + ((size_t)(ks << 3) << 9) + lo8;
        #pragma unroll
        for (int nf = 0; nf < 8; ++nf) {
            bf16x8 b = *(const bf16x8*)(wp + (nf << 9));
            acc2[nf] = __builtin_amdgcn_mfma_f32_16x16x32_bf16(a, b, acc2[nf], 0, 0, 0);
        }
    }

    float b2v[8], gv[8], bvv[8];
    #pragma unroll
    for (int nf = 0; nf < 8; ++nf) {
        b2v[nf] = b2[nf * 16 + c16];
        gv[nf]  = lng[nf * 16 + c16];
        bvv[nf] = lnb[nf * 16 + c16];
    }

    float s[4] = {0.f, 0.f, 0.f, 0.f}, q[4] = {0.f, 0.f, 0.f, 0.f};
    #pragma unroll
    for (int nf = 0; nf < 8; ++nf)
        #pragma unroll
        for (int r = 0; r < 4; ++r) {
            float zz = acc2[nf][r] + b2v[nf];
            acc2[nf][r] = zz;
            s[r] += zz;
            q[r] += zz * zz;
        }
    #pragma unroll
    for (int m = 1; m <= 8; m <<= 1)
        #pragma unroll
        for (int r = 0; r < 4; ++r) {
            s[r] += __shfl_xor(s[r], m, 64);
            q[r] += __shfl_xor(q[r], m, 64);
        }

    #pragma unroll
    for (int r = 0; r < 4; ++r) {
        const float mu   = s[r] * (1.0f / 128.0f);
        const float var  = q[r] * (1.0f / 128.0f) - mu * mu;
        const float rstd = rsqrtf(var + LN_EPS);
        const int row = r0g + wrow0 + kq * 4 + r;
        if (row >= NNODES) continue;
        const size_t orow = (size_t)row * D;
        #pragma unroll
        for (int nf = 0; nf < 8; ++nf) {
            const int col = nf * 16 + c16;
            float o = (acc2[nf][r] - mu) * rstd * gv[nf] + bvv[nf] + x[orow + col];
            nodes_out[orow + col] = o;
        }
    }
}

extern "C" void kernel_launch(void* const* d_in, const int* in_sizes, int n_in,
                              void* d_out, int out_size, void* d_ws, size_t ws_size,
                              hipStream_t stream) {
    (void)in_sizes; (void)n_in; (void)ws_size; (void)out_size;

    const float* x         = (const float*)d_in[0];
    const float* edge_attr = (const float*)d_in[1];
    const int*   edge_idx  = (const int*)  d_in[2];
    const float* eW1 = (const float*)d_in[3];
    const float* eb1 = (const float*)d_in[4];
    const float* eW2 = (const float*)d_in[5];
    const float* eb2 = (const float*)d_in[6];
    const float* elg = (const float*)d_in[7];
    const float* elb = (const float*)d_in[8];
    const float* nW1 = (const float*)d_in[9];
    const float* nb1 = (const float*)d_in[10];
    const float* nW2 = (const float*)d_in[11];
    const float* nb2 = (const float*)d_in[12];
    const float* nlg = (const float*)d_in[13];
    const float* nlb = (const float*)d_in[14];

    float* out       = (float*)d_out;
    float* nodes_out = out;                        // doubles as agg accumulator
    float* edges_out = out + (size_t)NNODES * D;

    __bf16* ws = (__bf16*)d_ws;

    prep_weights<<<(WS_ELEMS + 255) / 256, 256, 0, stream>>>(eW1, eW2, nW1, nW2, ws);

    hipMemsetAsync(nodes_out, 0, (size_t)NNODES * D * sizeof(float), stream);

    edge_kernel_pw<<<512, BLK, 0, stream>>>(
        x, edge_attr, edge_idx,
        ws + EW1F_OFF, eb1, ws + EW2F_OFF, eb2, elg, elb,
        edges_out, nodes_out);

    node_kernel<<<(NNODES + TN - 1) / TN, BLK, 0, stream>>>(
        x, nodes_out,
        ws + NW1F_OFF, nb1, ws + NW2F_OFF, nb2, nlg, nlb,
        nodes_out);
}

// Round 10
// 450.846 us; speedup vs baseline: 2.9700x; 1.2164x over previous
//
#include <hip/hip_runtime.h>
#include <hip/hip_bf16.h>

#define D       128
#define NNODES  50000
#define NEDGES  600000
#define TE      64           // edges per block (9375 blocks)
#define TN      64           // nodes per block
#define BLK     256
#define LN_EPS  1e-5f

typedef float  fx4    __attribute__((ext_vector_type(4)));
typedef float  f32x4  __attribute__((ext_vector_type(4)));
typedef __bf16 bf16x4 __attribute__((ext_vector_type(4)));
typedef __bf16 bf16x8 __attribute__((ext_vector_type(8)));

// ---- d_ws layout ----
// Fragment-major weights (bf16): frag[kstep][nf][lane(64)][8], 512 bf16/frag.
#define EW1F_OFF 0                         // K=384: 12 ksteps * 8 nf
#define EW2F_OFF (128 * 384)
#define NW1F_OFF (EW2F_OFF + 128 * 128)
#define NW2F_OFF (NW1F_OFF + 128 * 256)
#define WS_ELEMS (NW2F_OFF + 128 * 128)    // 114688 bf16
#define W_BYTES  (WS_ELEMS * 2)
// bf16 aggregation buffer
#define AGGB_OFF ((size_t)W_BYTES)
#define WS_NEED  (AGGB_OFF + (size_t)NNODES * D * 2)   // ~13 MB

__device__ __forceinline__ float silu_f(float z) {
    return z * (1.0f / (1.0f + __expf(-z)));
}

// ---------------------------------------------------------------------------
// Weight prep: f32 [K][128] -> bf16 fragment-major frag[ks][nf][lane][8]
// ---------------------------------------------------------------------------
__global__ __launch_bounds__(256) void prep_weights(
    const float* __restrict__ eW1, const float* __restrict__ eW2,
    const float* __restrict__ nW1, const float* __restrict__ nW2,
    __bf16* __restrict__ ws)
{
    int idx = blockIdx.x * 256 + threadIdx.x;
    if (idx >= WS_ELEMS) return;
    const float* src;
    int local;
    if (idx < EW2F_OFF)      { src = eW1; local = idx; }
    else if (idx < NW1F_OFF) { src = eW2; local = idx - EW2F_OFF; }
    else if (idx < NW2F_OFF) { src = nW1; local = idx - NW1F_OFF; }
    else                     { src = nW2; local = idx - NW2F_OFF; }
    const int f   = local >> 9;
    const int rem = local & 511;
    const int l   = rem >> 3;
    const int j   = rem & 7;
    const int ks  = f >> 3;
    const int nf  = f & 7;
    const int n   = (nf << 4) + (l & 15);
    const int k   = (ks << 5) + ((l >> 4) << 3) + j;
    ws[idx] = (__bf16)src[(size_t)k * D + n];
}

// ---------------------------------------------------------------------------
// Edge kernel (round-6 structure): 64 edges/block, 4 waves x 16 rows.
// PK=true : aggregation via packed-bf16 atomics into aggB (2 cols/op).
// PK=false: f32 atomics into aggF.
// ---------------------------------------------------------------------------
template<bool PK>
__global__ __launch_bounds__(BLK, 4) void edge_kernel(
    const float* __restrict__ x,
    const float* __restrict__ edge_attr,
    const int*   __restrict__ edge_index,
    const __bf16* __restrict__ W1f,
    const float* __restrict__ b1,
    const __bf16* __restrict__ W2f,
    const float* __restrict__ b2,
    const float* __restrict__ lng, const float* __restrict__ lnb,
    float* __restrict__ edges_out,
    float* __restrict__ aggF,
    __hip_bfloat162* __restrict__ aggB)
{
    __shared__ __bf16 in_t[TE][264];   // 256 used; h1 aliases cols 0..127 later
    __shared__ int    src_s[TE], dst_s[TE];

    const int tid = threadIdx.x;
    const int e0g = blockIdx.x * TE;

    if (tid < TE) {
        src_s[tid] = edge_index[e0g + tid];            // edge_index[0] = src (j)
        dst_s[tid] = edge_index[NEDGES + e0g + tid];   // edge_index[1] = dst (i)
    }
    __syncthreads();

    const int lane  = tid & 63;
    const int wid   = tid >> 6;
    const int wrow0 = wid << 4;        // wave's 16 rows
    const int c16   = lane & 15;
    const int kq    = lane >> 4;
    const int ks8   = kq << 3;
    const int lo8   = lane << 3;       // fragment lane offset (bf16 elems)

    // ---- edge_attr A-fragments straight from global (block-contiguous) ----
    bf16x8 aE[4];
    {
        const float* ep = edge_attr + (size_t)(e0g + wrow0 + c16) * D + ks8;
        #pragma unroll
        for (int ks2 = 0; ks2 < 4; ++ks2) {
            fx4 v0 = *(const fx4*)(ep + (ks2 << 5));
            fx4 v1 = *(const fx4*)(ep + (ks2 << 5) + 4);
            bf16x8 a;
            #pragma unroll
            for (int j = 0; j < 4; ++j) { a[j] = (__bf16)v0[j]; a[j + 4] = (__bf16)v1[j]; }
            aE[ks2] = a;
        }
    }

    // ---- stage x[dst] | x[src] ----
    #pragma unroll
    for (int it = 0; it < 8; ++it) {
        const int idx = tid + it * BLK;
        const int e   = idx >> 5;
        const int c4  = (idx & 31) << 2;
        fx4 v = *(const fx4*)&x[(size_t)dst_s[e] * D + c4];
        bf16x4 h;
        #pragma unroll
        for (int j = 0; j < 4; ++j) h[j] = (__bf16)v[j];
        *(bf16x4*)&in_t[e][c4] = h;
    }
    #pragma unroll
    for (int it = 0; it < 8; ++it) {
        const int idx = tid + it * BLK;
        const int e   = idx >> 5;
        const int c4  = (idx & 31) << 2;
        fx4 v = *(const fx4*)&x[(size_t)src_s[e] * D + c4];
        bf16x4 h;
        #pragma unroll
        for (int j = 0; j < 4; ++j) h[j] = (__bf16)v[j];
        *(bf16x4*)&in_t[e][128 + c4] = h;
    }
    __syncthreads();

    // ---- GEMM1: [16,384] @ [384,128] per wave ----
    f32x4 acc[8];
    #pragma unroll
    for (int nf = 0; nf < 8; ++nf) acc[nf] = (f32x4){0.f, 0.f, 0.f, 0.f};

    #pragma unroll
    for (int ks = 0; ks < 12; ++ks) {
        bf16x8 a = (ks < 8) ? *(const bf16x8*)&in_t[wrow0 + c16][(ks << 5) + ks8]
                            : aE[ks - 8];
        const __bf16* wp = W1f + ((size_t)(ks << 3) << 9) + lo8;
        #pragma unroll
        for (int nf = 0; nf < 8; ++nf) {
            bf16x8 b = *(const bf16x8*)(wp + (nf << 9));
            acc[nf] = __builtin_amdgcn_mfma_f32_16x16x32_bf16(a, b, acc[nf], 0, 0, 0);
        }
    }

    // SiLU + bias -> h1 aliased into in_t cols 0..127 (wave-private rows)
    #pragma unroll
    for (int nf = 0; nf < 8; ++nf) {
        const float bb = b1[nf * 16 + c16];
        #pragma unroll
        for (int r = 0; r < 4; ++r) {
            float h = silu_f(acc[nf][r] + bb);
            in_t[wrow0 + kq * 4 + r][nf * 16 + c16] = (__bf16)h;
        }
    }

    // ---- GEMM2: [16,128] @ [128,128] per wave ----
    f32x4 acc2[8];
    #pragma unroll
    for (int nf = 0; nf < 8; ++nf) acc2[nf] = (f32x4){0.f, 0.f, 0.f, 0.f};

    #pragma unroll
    for (int ks = 0; ks < 4; ++ks) {
        bf16x8 a = *(const bf16x8*)&in_t[wrow0 + c16][(ks << 5) + ks8];
        const __bf16* wp = W2f + ((size_t)(ks << 3) << 9) + lo8;
        #pragma unroll
        for (int nf = 0; nf < 8; ++nf) {
            bf16x8 b = *(const bf16x8*)(wp + (nf << 9));
            acc2[nf] = __builtin_amdgcn_mfma_f32_16x16x32_bf16(a, b, acc2[nf], 0, 0, 0);
        }
    }

    // ---- bias + LayerNorm + store + scatter-add ----
    float b2v[8], gv[8], bvv[8];
    #pragma unroll
    for (int nf = 0; nf < 8; ++nf) {
        b2v[nf] = b2[nf * 16 + c16];
        gv[nf]  = lng[nf * 16 + c16];
        bvv[nf] = lnb[nf * 16 + c16];
    }

    float s[4] = {0.f, 0.f, 0.f, 0.f}, q[4] = {0.f, 0.f, 0.f, 0.f};
    #pragma unroll
    for (int nf = 0; nf < 8; ++nf)
        #pragma unroll
        for (int r = 0; r < 4; ++r) {
            float zz = acc2[nf][r] + b2v[nf];
            acc2[nf][r] = zz;
            s[r] += zz;
            q[r] += zz * zz;
        }
    #pragma unroll
    for (int m = 1; m <= 8; m <<= 1)
        #pragma unroll
        for (int r = 0; r < 4; ++r) {
            s[r] += __shfl_xor(s[r], m, 64);
            q[r] += __shfl_xor(q[r], m, 64);
        }

    #pragma unroll
    for (int r = 0; r < 4; ++r) {
        const float mu   = s[r] * (1.0f / 128.0f);
        const float var  = q[r] * (1.0f / 128.0f) - mu * mu;
        const float rstd = rsqrtf(var + LN_EPS);
        const int row = wrow0 + kq * 4 + r;
        const size_t erow = (size_t)(e0g + row) * D;
        const int dn = dst_s[row];
        #pragma unroll
        for (int nf = 0; nf < 8; ++nf) {
            const int col = nf * 16 + c16;
            float o = (acc2[nf][r] - mu) * rstd * gv[nf] + bvv[nf];
            edges_out[erow + col] = o;
            if constexpr (PK) {
                // pair with neighbor lane (c16^1): lane with even c16 issues
                // one packed-bf16 atomic covering cols (col, col+1)
                float on = __shfl_xor(o, 1, 64);
                if ((c16 & 1) == 0) {
                    __hip_bfloat162 v;
                    v.x = __float2bfloat16(o);
                    v.y = __float2bfloat16(on);
                    unsafeAtomicAdd(&aggB[((size_t)dn * D + col) >> 1], v);
                }
            } else {
                atomicAdd(aggF + (size_t)dn * D + col, o);
            }
        }
    }
}

// ---------------------------------------------------------------------------
// Node kernel: 64 nodes/block; in = [x, agg] (256).
// BF16AGG=true: agg read as bf16 (aggB); else f32 (aggF).
// ---------------------------------------------------------------------------
template<bool BF16AGG>
__global__ __launch_bounds__(BLK, 4) void node_kernel(
    const float* __restrict__ x,
    const float* __restrict__ aggF,
    const __bf16* __restrict__ aggB,
    const __bf16* __restrict__ W1f,
    const float* __restrict__ b1,
    const __bf16* __restrict__ W2f,
    const float* __restrict__ b2,
    const float* __restrict__ lng, const float* __restrict__ lnb,
    float* __restrict__ nodes_out)
{
    __shared__ __bf16 in_t[TN][264];   // 256 used; h1 aliases cols 0..127

    const int tid = threadIdx.x;
    const int r0g = blockIdx.x * TN;

    #pragma unroll
    for (int it = 0; it < 8; ++it) {
        const int idx = tid + it * BLK;
        const int e   = idx >> 5;
        const int c4  = (idx & 31) << 2;
        const int row = r0g + e;
        fx4 v = {0.f, 0.f, 0.f, 0.f};
        if (row < NNODES) v = *(const fx4*)&x[(size_t)row * D + c4];
        bf16x4 h;
        #pragma unroll
        for (int j = 0; j < 4; ++j) h[j] = (__bf16)v[j];
        *(bf16x4*)&in_t[e][c4] = h;
    }
    #pragma unroll
    for (int it = 0; it < 8; ++it) {
        const int idx = tid + it * BLK;
        const int e   = idx >> 5;
        const int c4  = (idx & 31) << 2;
        const int row = r0g + e;
        bf16x4 h = {(__bf16)0.f, (__bf16)0.f, (__bf16)0.f, (__bf16)0.f};
        if (row < NNODES) {
            if constexpr (BF16AGG) {
                h = *(const bf16x4*)&aggB[(size_t)row * D + c4];
            } else {
                fx4 v = *(const fx4*)&aggF[(size_t)row * D + c4];
                #pragma unroll
                for (int j = 0; j < 4; ++j) h[j] = (__bf16)v[j];
            }
        }
        *(bf16x4*)&in_t[e][128 + c4] = h;
    }
    __syncthreads();

    const int lane  = tid & 63;
    const int wid   = tid >> 6;
    const int wrow0 = wid << 4;
    const int c16   = lane & 15;
    const int kq    = lane >> 4;
    const int ks8   = kq << 3;
    const int lo8   = lane << 3;

    f32x4 acc[8];
    #pragma unroll
    for (int nf = 0; nf < 8; ++nf) acc[nf] = (f32x4){0.f, 0.f, 0.f, 0.f};

    #pragma unroll
    for (int ks = 0; ks < 8; ++ks) {
        bf16x8 a = *(const bf16x8*)&in_t[wrow0 + c16][(ks << 5) + ks8];
        const __bf16* wp = W1f + ((size_t)(ks << 3) << 9) + lo8;
        #pragma unroll
        for (int nf = 0; nf < 8; ++nf) {
            bf16x8 b = *(const bf16x8*)(wp + (nf << 9));
            acc[nf] = __builtin_amdgcn_mfma_f32_16x16x32_bf16(a, b, acc[nf], 0, 0, 0);
        }
    }

    #pragma unroll
    for (int nf = 0; nf < 8; ++nf) {
        const float bb = b1[nf * 16 + c16];
        #pragma unroll
        for (int r = 0; r < 4; ++r) {
            float h = silu_f(acc[nf][r] + bb);
            in_t[wrow0 + kq * 4 + r][nf * 16 + c16] = (__bf16)h;
        }
    }

    f32x4 acc2[8];
    #pragma unroll
    for (int nf = 0; nf < 8; ++nf) acc2[nf] = (f32x4){0.f, 0.f, 0.f, 0.f};

    #pragma unroll
    for (int ks = 0; ks < 4; ++ks) {
        bf16x8 a = *(const bf16x8*)&in_t[wrow0 + c16][(ks << 5) + ks8];
        const __bf16* wp = W2f + ((size_t)(ks << 3) << 9) + lo8;
        #pragma unroll
        for (int nf = 0; nf < 8; ++nf) {
            bf16x8 b = *(const bf16x8*)(wp + (nf << 9));
            acc2[nf] = __builtin_amdgcn_mfma_f32_16x16x32_bf16(a, b, acc2[nf], 0, 0, 0);
        }
    }

    float b2v[8], gv[8], bvv[8];
    #pragma unroll
    for (int nf = 0; nf < 8; ++nf) {
        b2v[nf] = b2[nf * 16 + c16];
        gv[nf]  = lng[nf * 16 + c16];
        bvv[nf] = lnb[nf * 16 + c16];
    }

    float s[4] = {0.f, 0.f, 0.f, 0.f}, q[4] = {0.f, 0.f, 0.f, 0.f};
    #pragma unroll
    for (int nf = 0; nf < 8; ++nf)
        #pragma unroll
        for (int r = 0; r < 4; ++r) {
            float zz = acc2[nf][r] + b2v[nf];
            acc2[nf][r] = zz;
            s[r] += zz;
            q[r] += zz * zz;
        }
    #pragma unroll
    for (int m = 1; m <= 8; m <<= 1)
        #pragma unroll
        for (int r = 0; r < 4; ++r) {
            s[r] += __shfl_xor(s[r], m, 64);
            q[r] += __shfl_xor(q[r], m, 64);
        }

    #pragma unroll
    for (int r = 0; r < 4; ++r) {
        const float mu   = s[r] * (1.0f / 128.0f);
        const float var  = q[r] * (1.0f / 128.0f) - mu * mu;
        const float rstd = rsqrtf(var + LN_EPS);
        const int row = r0g + wrow0 + kq * 4 + r;
        if (row >= NNODES) continue;
        const size_t orow = (size_t)row * D;
        #pragma unroll
        for (int nf = 0; nf < 8; ++nf) {
            const int col = nf * 16 + c16;
            float o = (acc2[nf][r] - mu) * rstd * gv[nf] + bvv[nf] + x[orow + col];
            nodes_out[orow + col] = o;
        }
    }
}

extern "C" void kernel_launch(void* const* d_in, const int* in_sizes, int n_in,
                              void* d_out, int out_size, void* d_ws, size_t ws_size,
                              hipStream_t stream) {
    (void)in_sizes; (void)n_in; (void)out_size;

    const float* x         = (const float*)d_in[0];
    const float* edge_attr = (const float*)d_in[1];
    const int*   edge_idx  = (const int*)  d_in[2];
    const float* eW1 = (const float*)d_in[3];
    const float* eb1 = (const float*)d_in[4];
    const float* eW2 = (const float*)d_in[5];
    const float* eb2 = (const float*)d_in[6];
    const float* elg = (const float*)d_in[7];
    const float* elb = (const float*)d_in[8];
    const float* nW1 = (const float*)d_in[9];
    const float* nb1 = (const float*)d_in[10];
    const float* nW2 = (const float*)d_in[11];
    const float* nb2 = (const float*)d_in[12];
    const float* nlg = (const float*)d_in[13];
    const float* nlb = (const float*)d_in[14];

    float* out       = (float*)d_out;
    float* nodes_out = out;
    float* edges_out = out + (size_t)NNODES * D;

    char*   wsb = (char*)d_ws;
    __bf16* ws  = (__bf16*)d_ws;

    prep_weights<<<(WS_ELEMS + 255) / 256, 256, 0, stream>>>(eW1, eW2, nW1, nW2, ws);

    if (ws_size >= WS_NEED) {
        // ---- packed-bf16 atomic aggregation path ----
        __bf16* aggB = (__bf16*)(wsb + AGGB_OFF);
        hipMemsetAsync(aggB, 0, (size_t)NNODES * D * 2, stream);

        edge_kernel<true><<<NEDGES / TE, BLK, 0, stream>>>(
            x, edge_attr, edge_idx,
            ws + EW1F_OFF, eb1, ws + EW2F_OFF, eb2, elg, elb,
            edges_out, nullptr, (__hip_bfloat162*)aggB);

        node_kernel<true><<<(NNODES + TN - 1) / TN, BLK, 0, stream>>>(
            x, nullptr, aggB,
            ws + NW1F_OFF, nb1, ws + NW2F_OFF, nb2, nlg, nlb,
            nodes_out);
    } else {
        // ---- fallback: f32 atomics into nodes_out (round-6 path) ----
        hipMemsetAsync(nodes_out, 0, (size_t)NNODES * D * sizeof(float), stream);

        edge_kernel<false><<<NEDGES / TE, BLK, 0, stream>>>(
            x, edge_attr, edge_idx,
            ws + EW1F_OFF, eb1, ws + EW2F_OFF, eb2, elg, elb,
            edges_out, nodes_out, nullptr);

        node_kernel<false><<<(NNODES + TN - 1) / TN, BLK, 0, stream>>>(
            x, nodes_out, nullptr,
            ws + NW1F_OFF, nb1, ws + NW2F_OFF, nb2, nlg, nlb,
            nodes_out);
    }
}